// Round 9
// baseline (14396.202 us; speedup 1.0000x reference)
//
#include <hip/hip_runtime.h>
#include <stdint.h>
#include <math.h>

#define B_ 64
#define S_ 512
#define I_ 128
#define H_ 2048
#define O_ 128
#define NWG 128
#define COLS 16
#define NTHREADS 256
#define SLAB (B_ * H_)      /* 131072 elements per h snapshot */
#define RSTR 20             /* sRed row stride in floats */
#define CAN64 0xFFFFFFFFFFFFFFFFull   /* 4x bf16 NaN: tanh can't produce */

typedef __attribute__((ext_vector_type(8))) __bf16 bf16x8;
typedef __attribute__((ext_vector_type(4))) float floatx4;
typedef __attribute__((ext_vector_type(4))) unsigned int uintx4;
typedef unsigned long long ull;

__device__ __forceinline__ unsigned short f2bf(float f) {
    unsigned u = __float_as_uint(f);
    unsigned r = u + 0x7fffu + ((u >> 16) & 1u);   // RNE
    return (unsigned short)(r >> 16);
}
__device__ __forceinline__ float bf2f(unsigned short h) {
    return __uint_as_float(((unsigned)h) << 16);
}
// tanh(x) = 1 - 2/(e^{2x}+1); err ~1e-6 << bf16 noise. Output in [-1,1],
// never NaN -> canary 0xFFFF (bf16 NaN) is unreachable.
__device__ __forceinline__ float fast_tanh(float x) {
    float e = __expf(2.0f * x);
    return 1.0f - 2.0f * __builtin_amdgcn_rcpf(e + 1.0f);
}

// retry loads: sc0 = bypass L1 (read own-XCD L2); sc0 sc1 = bypass L1+L2
// (read coherence point -> correct regardless of XCD mapping)
__device__ __forceinline__ uintx4 gload_sc0(const void* p) {
    uintx4 r;
    asm volatile("global_load_dwordx4 %0, %1, off sc0\n\ts_waitcnt vmcnt(0)"
                 : "=v"(r) : "v"(p) : "memory");
    return r;
}
__device__ __forceinline__ uintx4 gload_sc0sc1(const void* p) {
    uintx4 r;
    asm volatile("global_load_dwordx4 %0, %1, off sc0 sc1\n\ts_waitcnt vmcnt(0)"
                 : "=v"(r) : "v"(p) : "memory");
    return r;
}

// ---- prep kernels -------------------------------------------------------
__global__ void k_wsplit(const float* __restrict__ whh, const float* __restrict__ mask,
                         unsigned short* __restrict__ hi, unsigned short* __restrict__ lo, int n) {
    int i = blockIdx.x * blockDim.x + threadIdx.x;
    int stride = gridDim.x * blockDim.x;
    for (; i < n; i += stride) {
        float w = whh[i] * mask[i];
        unsigned short h = f2bf(w);
        hi[i] = h;
        lo[i] = f2bf(w - bf2f(h));
    }
}
__global__ void k_split(const float* __restrict__ src,
                        unsigned short* __restrict__ hi, unsigned short* __restrict__ lo, int n) {
    int i = blockIdx.x * blockDim.x + threadIdx.x;
    int stride = gridDim.x * blockDim.x;
    for (; i < n; i += stride) {
        float w = src[i];
        unsigned short h = f2bf(w);
        hi[i] = h;
        lo[i] = f2bf(w - bf2f(h));
    }
}
__global__ void k_cast(const float* __restrict__ src, unsigned short* __restrict__ dst, int n) {
    int i = blockIdx.x * blockDim.x + threadIdx.x;
    int stride = gridDim.x * blockDim.x;
    for (; i < n; i += stride) dst[i] = f2bf(src[i]);
}

// ---- persistent recurrence kernel --------------------------------------
// r5 skeleton (128 WGs x 256 thr, WG owns 16 cols, split-K over 4 waves)
// with the flag protocol DELETED. Sync = canary-validated data:
//  - slabs 1..S pre-filled 0xFF (bf16 NaN, unreachable output value)
//  - producers: reduce -> tanh -> 16-B sc1 write-through store -> continue.
//    NO vmcnt drain, NO flag, NO second barrier.
//  - consumers: depth-4 plain b128 prefetch pipeline; per-chunk validate
//    each 8-B half != canary (each half is half of one producer 16-B store,
//    written exactly once: fresh-or-canary). Stale -> retry sc0 once, then
//    sc0sc1 (MALL truth; correct regardless of XCD mapping). Per-chunk
//    gating: a late producer stalls only its dependent chunks.
__global__ __launch_bounds__(NTHREADS, 1) void k_rnn(
    const unsigned short* __restrict__ whi, const unsigned short* __restrict__ wlo,
    const unsigned short* __restrict__ wihh, const unsigned short* __restrict__ wihl,
    const unsigned short* __restrict__ xbf, const float* __restrict__ bih,
    unsigned short* hs)
{
    __shared__ float sRed[2][4 * 64 * RSTR];
    __shared__ float sBih[COLS];

    const int tid  = threadIdx.x;
    const int wg   = blockIdx.x;
    const int j0   = wg * COLS;
    const int w    = tid >> 6;
    const int lane = tid & 63;
    const int q    = lane >> 4;
    const int nn   = lane & 15;
    const int kb   = w * 512;   // this wave's k range in H
    const int xkb  = w * 32;    // this wave's k range in I

    if (tid < COLS) sBih[tid] = bih[j0 + tid];

    // W fragments (r5 layout; compiler reloads from L2 per step - accepted)
    bf16x8 wh[16], wl[16], bxh, bxl;
    {
        const size_t wrow = (size_t)(j0 + nn) * H_ + (size_t)(kb + q * 8);
#pragma unroll
        for (int ks = 0; ks < 16; ++ks) {
            wh[ks] = *(const bf16x8*)&whi[wrow + ks * 32];
            wl[ks] = *(const bf16x8*)&wlo[wrow + ks * 32];
        }
        const size_t xrow = (size_t)(j0 + nn) * I_ + (size_t)(xkb + q * 8);
        bxh = *(const bf16x8*)&wihh[xrow];
        bxl = *(const bf16x8*)&wihl[xrow];
    }

#pragma unroll 1
    for (int t = 0; t < S_; ++t) {
        const unsigned short* hp = hs + (size_t)t * SLAB;
        floatx4 a0 = {0.f, 0.f, 0.f, 0.f}, a1 = a0, a2 = a0, a3 = a0;

        // h-independent x-projection first
        {
            const size_t xoff = (size_t)t * I_ + xkb + q * 8;
            bf16x8 x0 = *(const bf16x8*)&xbf[(size_t)(nn)      * (S_ * I_) + xoff];
            bf16x8 x1 = *(const bf16x8*)&xbf[(size_t)(16 + nn) * (S_ * I_) + xoff];
            bf16x8 x2 = *(const bf16x8*)&xbf[(size_t)(32 + nn) * (S_ * I_) + xoff];
            bf16x8 x3 = *(const bf16x8*)&xbf[(size_t)(48 + nn) * (S_ * I_) + xoff];
            a0 = __builtin_amdgcn_mfma_f32_16x16x32_bf16(x0, bxh, a0, 0, 0, 0);
            a1 = __builtin_amdgcn_mfma_f32_16x16x32_bf16(x1, bxh, a1, 0, 0, 0);
            a2 = __builtin_amdgcn_mfma_f32_16x16x32_bf16(x2, bxh, a2, 0, 0, 0);
            a3 = __builtin_amdgcn_mfma_f32_16x16x32_bf16(x3, bxh, a3, 0, 0, 0);
            a0 = __builtin_amdgcn_mfma_f32_16x16x32_bf16(x0, bxl, a0, 0, 0, 0);
            a1 = __builtin_amdgcn_mfma_f32_16x16x32_bf16(x1, bxl, a1, 0, 0, 0);
            a2 = __builtin_amdgcn_mfma_f32_16x16x32_bf16(x2, bxl, a2, 0, 0, 0);
            a3 = __builtin_amdgcn_mfma_f32_16x16x32_bf16(x3, bxl, a3, 0, 0, 0);
        }

        // K-loop with canary-validated depth-4 prefetch pipeline
        union U { uintx4 qd; ull u[2]; bf16x8 v; };
        U P[4][4];   // [slot][row-group]
#define HADDR(g_, ks_) ((const uintx4*)(hp + (size_t)((g_) * 16 + nn) * H_ + kb + (ks_) * 32 + q * 8))
#pragma unroll
        for (int s = 0; s < 4; ++s) {
            P[s][0].qd = *HADDR(0, s); P[s][1].qd = *HADDR(1, s);
            P[s][2].qd = *HADDR(2, s); P[s][3].qd = *HADDR(3, s);
        }
#pragma unroll 1
        for (int ks = 0; ks < 16; ++ks) {
            const int s = ks & 3;
            int tries = 0;
            for (;;) {
                bool stale = (P[s][0].u[0] == CAN64) | (P[s][0].u[1] == CAN64) |
                             (P[s][1].u[0] == CAN64) | (P[s][1].u[1] == CAN64) |
                             (P[s][2].u[0] == CAN64) | (P[s][2].u[1] == CAN64) |
                             (P[s][3].u[0] == CAN64) | (P[s][3].u[1] == CAN64);
                if (__ballot(stale) == 0ull) break;
                if (tries == 0) {
                    P[s][0].qd = gload_sc0(HADDR(0, ks));
                    P[s][1].qd = gload_sc0(HADDR(1, ks));
                    P[s][2].qd = gload_sc0(HADDR(2, ks));
                    P[s][3].qd = gload_sc0(HADDR(3, ks));
                } else {
                    P[s][0].qd = gload_sc0sc1(HADDR(0, ks));
                    P[s][1].qd = gload_sc0sc1(HADDR(1, ks));
                    P[s][2].qd = gload_sc0sc1(HADDR(2, ks));
                    P[s][3].qd = gload_sc0sc1(HADDR(3, ks));
                }
                ++tries;
            }
            a0 = __builtin_amdgcn_mfma_f32_16x16x32_bf16(P[s][0].v, wh[ks], a0, 0, 0, 0);
            a1 = __builtin_amdgcn_mfma_f32_16x16x32_bf16(P[s][1].v, wh[ks], a1, 0, 0, 0);
            a2 = __builtin_amdgcn_mfma_f32_16x16x32_bf16(P[s][2].v, wh[ks], a2, 0, 0, 0);
            a3 = __builtin_amdgcn_mfma_f32_16x16x32_bf16(P[s][3].v, wh[ks], a3, 0, 0, 0);
            a0 = __builtin_amdgcn_mfma_f32_16x16x32_bf16(P[s][0].v, wl[ks], a0, 0, 0, 0);
            a1 = __builtin_amdgcn_mfma_f32_16x16x32_bf16(P[s][1].v, wl[ks], a1, 0, 0, 0);
            a2 = __builtin_amdgcn_mfma_f32_16x16x32_bf16(P[s][2].v, wl[ks], a2, 0, 0, 0);
            a3 = __builtin_amdgcn_mfma_f32_16x16x32_bf16(P[s][3].v, wl[ks], a3, 0, 0, 0);
            if (ks < 12) {
                P[s][0].qd = *HADDR(0, ks + 4); P[s][1].qd = *HADDR(1, ks + 4);
                P[s][2].qd = *HADDR(2, ks + 4); P[s][3].qd = *HADDR(3, ks + 4);
            }
        }
#undef HADDR

        // wave partials -> LDS (double buffer by step parity)
        float* sr = sRed[t & 1];
#pragma unroll
        for (int r = 0; r < 4; ++r) {
            sr[(w * 64 +      q * 4 + r) * RSTR + nn] = a0[r];
            sr[(w * 64 + 16 + q * 4 + r) * RSTR + nn] = a1[r];
            sr[(w * 64 + 32 + q * 4 + r) * RSTR + nn] = a2[r];
            sr[(w * 64 + 48 + q * 4 + r) * RSTR + nn] = a3[r];
        }
        __syncthreads();   // the ONE barrier per step

        // reduce 4 waves, +bih, tanh, pack, 16-B sc1 store. Fire & forget:
        // the data itself is the sync token (canary scheme).
        if (tid < 128) {
            const int m  = tid >> 1;
            const int n0 = (tid & 1) * 8;
            floatx4 sA = *(const floatx4*)&sr[(0 * 64 + m) * RSTR + n0];
            floatx4 sB = *(const floatx4*)&sr[(0 * 64 + m) * RSTR + n0 + 4];
            sA += *(const floatx4*)&sr[(1 * 64 + m) * RSTR + n0];
            sB += *(const floatx4*)&sr[(1 * 64 + m) * RSTR + n0 + 4];
            sA += *(const floatx4*)&sr[(2 * 64 + m) * RSTR + n0];
            sB += *(const floatx4*)&sr[(2 * 64 + m) * RSTR + n0 + 4];
            sA += *(const floatx4*)&sr[(3 * 64 + m) * RSTR + n0];
            sB += *(const floatx4*)&sr[(3 * 64 + m) * RSTR + n0 + 4];
            unsigned short u0 = f2bf(fast_tanh(sA[0] + sBih[n0 + 0]));
            unsigned short u1 = f2bf(fast_tanh(sA[1] + sBih[n0 + 1]));
            unsigned short u2 = f2bf(fast_tanh(sA[2] + sBih[n0 + 2]));
            unsigned short u3 = f2bf(fast_tanh(sA[3] + sBih[n0 + 3]));
            unsigned short u4 = f2bf(fast_tanh(sB[0] + sBih[n0 + 4]));
            unsigned short u5 = f2bf(fast_tanh(sB[1] + sBih[n0 + 5]));
            unsigned short u6 = f2bf(fast_tanh(sB[2] + sBih[n0 + 6]));
            unsigned short u7 = f2bf(fast_tanh(sB[3] + sBih[n0 + 7]));
            uintx4 pk;
            pk.x = (unsigned)u0 | ((unsigned)u1 << 16);
            pk.y = (unsigned)u2 | ((unsigned)u3 << 16);
            pk.z = (unsigned)u4 | ((unsigned)u5 << 16);
            pk.w = (unsigned)u6 | ((unsigned)u7 << 16);
            unsigned short* dst =
                &hs[(size_t)(t + 1) * SLAB + (size_t)m * H_ + j0 + n0];
            asm volatile("global_store_dwordx4 %0, %1, off sc1"
                         :: "v"(dst), "v"(pk) : "memory");
        }
        // no drain, no flag, no second barrier
    }
}

// ---- output projection: out[b,t,o] = hs[t+1][b,:] . Who[o,:] + bho ------
__global__ __launch_bounds__(NTHREADS) void k_out(
    const unsigned short* __restrict__ hflat, const unsigned short* __restrict__ who,
    const float* __restrict__ bho, float* __restrict__ out)
{
    const int tid = threadIdx.x;
    const int w = tid >> 6, lane = tid & 63, q = lane >> 4, nn = lane & 15;
    const size_t r0 = ((size_t)blockIdx.x * 4 + w) * 16;   // row = t*64+b
    floatx4 acc[8];
#pragma unroll
    for (int i = 0; i < 8; ++i) acc[i] = floatx4{0.f, 0.f, 0.f, 0.f};
    for (int ks = 0; ks < 64; ++ks) {
        const int kk = ks * 32 + q * 8;
        bf16x8 a = *(const bf16x8*)&hflat[(r0 + nn) * H_ + kk];
#pragma unroll
        for (int nt = 0; nt < 8; ++nt) {
            bf16x8 b = *(const bf16x8*)&who[(size_t)(nt * 16 + nn) * H_ + kk];
            acc[nt] = __builtin_amdgcn_mfma_f32_16x16x32_bf16(a, b, acc[nt], 0, 0, 0);
        }
    }
#pragma unroll
    for (int nt = 0; nt < 8; ++nt) {
#pragma unroll
        for (int r = 0; r < 4; ++r) {
            size_t rr = r0 + q * 4 + r;
            int t = (int)(rr >> 6), b = (int)(rr & 63);
            int o = nt * 16 + nn;
            out[(size_t)b * (S_ * O_) + (size_t)t * O_ + o] = acc[nt][r] + bho[o];
        }
    }
}

// ---- host ----------------------------------------------------------------
extern "C" void kernel_launch(void* const* d_in, const int* in_sizes, int n_in,
                              void* d_out, int out_size, void* d_ws, size_t ws_size,
                              hipStream_t stream) {
    const float* x    = (const float*)d_in[0];
    const float* Wih  = (const float*)d_in[1];
    const float* bih  = (const float*)d_in[2];
    const float* Whh  = (const float*)d_in[3];
    const float* Who  = (const float*)d_in[4];
    const float* bho  = (const float*)d_in[5];
    const float* mask = (const float*)d_in[6];
    float* out = (float*)d_out;

    char* ws = (char*)d_ws;
    constexpr size_t HS_OFF   = 0;
    constexpr size_t HS_BYTES = (size_t)(S_ + 1) * SLAB * 2;
    constexpr size_t WHI_OFF  = HS_OFF + HS_BYTES;
    constexpr size_t WLO_OFF  = WHI_OFF + (size_t)H_ * H_ * 2;
    constexpr size_t XBF_OFF  = WLO_OFF + (size_t)H_ * H_ * 2;
    constexpr size_t WIHH_OFF = XBF_OFF + (size_t)B_ * S_ * I_ * 2;
    constexpr size_t WIHL_OFF = WIHH_OFF + (size_t)H_ * I_ * 2;
    constexpr size_t WHO_OFF  = WIHL_OFF + (size_t)H_ * I_ * 2;
    constexpr size_t WS_NEED  = WHO_OFF + (size_t)O_ * H_ * 2;
    if (ws_size < WS_NEED) return;

    unsigned short* hs    = (unsigned short*)(ws + HS_OFF);
    unsigned short* whi   = (unsigned short*)(ws + WHI_OFF);
    unsigned short* wlo   = (unsigned short*)(ws + WLO_OFF);
    unsigned short* xbf   = (unsigned short*)(ws + XBF_OFF);
    unsigned short* wihh  = (unsigned short*)(ws + WIHH_OFF);
    unsigned short* wihl  = (unsigned short*)(ws + WIHL_OFF);
    unsigned short* whobf = (unsigned short*)(ws + WHO_OFF);

    hipMemsetAsync(hs, 0, (size_t)SLAB * 2, stream);                 // h(0)=0
    hipMemsetAsync(hs + SLAB, 0xFF, (size_t)S_ * SLAB * 2, stream);  // canary

    k_wsplit<<<1024, 256, 0, stream>>>(Whh, mask, whi, wlo, H_ * H_);
    k_split <<<256, 256, 0, stream>>>(Wih, wihh, wihl, H_ * I_);
    k_cast  <<<256, 256, 0, stream>>>(Who, whobf, O_ * H_);
    k_cast  <<<1024, 256, 0, stream>>>(x, xbf, B_ * S_ * I_);

    k_rnn<<<NWG, NTHREADS, 0, stream>>>(whi, wlo, wihh, wihl, xbf, bih, hs);
    k_out<<<512, NTHREADS, 0, stream>>>(hs + SLAB, whobf, bho, out);
}

// Round 10
// 4870.635 us; speedup vs baseline: 2.9557x; 2.9557x over previous
//
#include <hip/hip_runtime.h>
#include <stdint.h>
#include <math.h>

#define B_ 64
#define S_ 512
#define I_ 128
#define H_ 2048
#define O_ 128
#define NWG 128
#define COLS 16
#define NTHREADS 256
#define SLAB (B_ * H_)      /* 131072 elements per h snapshot */
#define RSTR 20             /* sRed row stride in floats */
#define FCPY 1024           /* flag copy stride in u32 (4 KB apart) */

typedef __attribute__((ext_vector_type(8))) __bf16 bf16x8;
typedef __attribute__((ext_vector_type(4))) float floatx4;
typedef __attribute__((ext_vector_type(4))) unsigned int uintx4;
typedef unsigned long long ull;

__device__ __forceinline__ unsigned short f2bf(float f) {
    unsigned u = __float_as_uint(f);
    unsigned r = u + 0x7fffu + ((u >> 16) & 1u);   // RNE
    return (unsigned short)(r >> 16);
}
__device__ __forceinline__ float bf2f(unsigned short h) {
    return __uint_as_float(((unsigned)h) << 16);
}
// tanh(x) = 1 - 2/(e^{2x}+1); err ~1e-6 << bf16 noise.
__device__ __forceinline__ float fast_tanh(float x) {
    float e = __expf(2.0f * x);
    return 1.0f - 2.0f * __builtin_amdgcn_rcpf(e + 1.0f);
}

// ---- prep kernels -------------------------------------------------------
__global__ void k_wsplit(const float* __restrict__ whh, const float* __restrict__ mask,
                         unsigned short* __restrict__ hi, unsigned short* __restrict__ lo, int n) {
    int i = blockIdx.x * blockDim.x + threadIdx.x;
    int stride = gridDim.x * blockDim.x;
    for (; i < n; i += stride) {
        float w = whh[i] * mask[i];
        unsigned short h = f2bf(w);
        hi[i] = h;
        lo[i] = f2bf(w - bf2f(h));
    }
}
__global__ void k_split(const float* __restrict__ src,
                        unsigned short* __restrict__ hi, unsigned short* __restrict__ lo, int n) {
    int i = blockIdx.x * blockDim.x + threadIdx.x;
    int stride = gridDim.x * blockDim.x;
    for (; i < n; i += stride) {
        float w = src[i];
        unsigned short h = f2bf(w);
        hi[i] = h;
        lo[i] = f2bf(w - bf2f(h));
    }
}
__global__ void k_cast(const float* __restrict__ src, unsigned short* __restrict__ dst, int n) {
    int i = blockIdx.x * blockDim.x + threadIdx.x;
    int stride = gridDim.x * blockDim.x;
    for (; i < n; i += stride) dst[i] = f2bf(src[i]);
}

// ---- persistent recurrence kernel --------------------------------------
// r5 skeleton: 128 WGs x 256 thr; WG owns 16 output cols; split-K over 4
// waves; h published via 16-B sc1 write-through stores + per-wave vmcnt
// drain; consumer h loads are plain b128 (fresh addresses each t -> can't
// be stale). Round-10 change: LOW-CONTENTION RENDEZVOUS.
//  - multicast publish: after drain+sync, lanes tid<8 store flag value
//    (t+1) to 8 REPLICATED flag regions (4 KB apart).
//  - poll: consumer group g = wg>>4 polls ITS OWN copy only; wave w reads
//    the single 128-B line holding its 32 producers' flags. <=16 coalesced
//    pollers per line + s_sleep backoff => release store never queues
//    behind a poll storm.
__global__ __launch_bounds__(NTHREADS, 1) void k_rnn(
    const unsigned short* __restrict__ whi, const unsigned short* __restrict__ wlo,
    const unsigned short* __restrict__ wihh, const unsigned short* __restrict__ wihl,
    const unsigned short* __restrict__ xbf, const float* __restrict__ bih,
    unsigned short* hs, unsigned int* flags)
{
    __shared__ float sRed[2][4 * 64 * RSTR];
    __shared__ float sBih[COLS];

    const int tid  = threadIdx.x;
    const int wg   = blockIdx.x;
    const int j0   = wg * COLS;
    const int w    = tid >> 6;
    const int lane = tid & 63;
    const int q    = lane >> 4;
    const int nn   = lane & 15;
    const int kb   = w * 512;   // this wave's k range in H
    const int xkb  = w * 32;    // this wave's k range in I
    const int grp  = wg >> 4;   // consumer octet -> which flag copy to poll

    if (tid < COLS) sBih[tid] = bih[j0 + tid];

    // poll address: line w of this group's private flag copy
    const unsigned int* const fpoll = flags + grp * FCPY + 32 * w + (lane & 31);

    // W fragments (r5 layout; compiler reloads from L2 per step - accepted)
    bf16x8 wh[16], wl[16], bxh, bxl;
    {
        const size_t wrow = (size_t)(j0 + nn) * H_ + (size_t)(kb + q * 8);
#pragma unroll
        for (int ks = 0; ks < 16; ++ks) {
            wh[ks] = *(const bf16x8*)&whi[wrow + ks * 32];
            wl[ks] = *(const bf16x8*)&wlo[wrow + ks * 32];
        }
        const size_t xrow = (size_t)(j0 + nn) * I_ + (size_t)(xkb + q * 8);
        bxh = *(const bf16x8*)&wihh[xrow];
        bxl = *(const bf16x8*)&wihl[xrow];
    }

#pragma unroll 1
    for (int t = 0; t < S_; ++t) {
        const unsigned short* hp = hs + (size_t)t * SLAB;
        floatx4 a0 = {0.f, 0.f, 0.f, 0.f}, a1 = a0, a2 = a0, a3 = a0;

        // h-independent x-projection first (overlaps producer latency)
        {
            const size_t xoff = (size_t)t * I_ + xkb + q * 8;
            bf16x8 x0 = *(const bf16x8*)&xbf[(size_t)(nn)      * (S_ * I_) + xoff];
            bf16x8 x1 = *(const bf16x8*)&xbf[(size_t)(16 + nn) * (S_ * I_) + xoff];
            bf16x8 x2 = *(const bf16x8*)&xbf[(size_t)(32 + nn) * (S_ * I_) + xoff];
            bf16x8 x3 = *(const bf16x8*)&xbf[(size_t)(48 + nn) * (S_ * I_) + xoff];
            a0 = __builtin_amdgcn_mfma_f32_16x16x32_bf16(x0, bxh, a0, 0, 0, 0);
            a1 = __builtin_amdgcn_mfma_f32_16x16x32_bf16(x1, bxh, a1, 0, 0, 0);
            a2 = __builtin_amdgcn_mfma_f32_16x16x32_bf16(x2, bxh, a2, 0, 0, 0);
            a3 = __builtin_amdgcn_mfma_f32_16x16x32_bf16(x3, bxh, a3, 0, 0, 0);
            a0 = __builtin_amdgcn_mfma_f32_16x16x32_bf16(x0, bxl, a0, 0, 0, 0);
            a1 = __builtin_amdgcn_mfma_f32_16x16x32_bf16(x1, bxl, a1, 0, 0, 0);
            a2 = __builtin_amdgcn_mfma_f32_16x16x32_bf16(x2, bxl, a2, 0, 0, 0);
            a3 = __builtin_amdgcn_mfma_f32_16x16x32_bf16(x3, bxl, a3, 0, 0, 0);
        }

        // wait for slab t: 32 producers of this wave's K-slice, own copy.
        // sc0sc1 = MALL truth (correct regardless of XCD mapping); backoff
        // keeps the line cold so the release store lands immediately.
        if (t > 0) {
            const unsigned want = (unsigned)t;
            for (;;) {
                unsigned v;
                asm volatile("global_load_dword %0, %1, off sc0 sc1\n\t"
                             "s_waitcnt vmcnt(0)"
                             : "=v"(v) : "v"(fpoll) : "memory");
                if (__ballot(v < want) == 0ull) break;
                __builtin_amdgcn_s_sleep(2);
            }
        }

        // recurrent K-slice: 16 ks steps, plain b128 h loads (fresh addrs)
#pragma unroll
        for (int ks = 0; ks < 16; ++ks) {
            const int kk = kb + ks * 32 + q * 8;
            bf16x8 h0 = *(const bf16x8*)&hp[(size_t)(nn)      * H_ + kk];
            bf16x8 h1 = *(const bf16x8*)&hp[(size_t)(16 + nn) * H_ + kk];
            bf16x8 h2 = *(const bf16x8*)&hp[(size_t)(32 + nn) * H_ + kk];
            bf16x8 h3 = *(const bf16x8*)&hp[(size_t)(48 + nn) * H_ + kk];
            a0 = __builtin_amdgcn_mfma_f32_16x16x32_bf16(h0, wh[ks], a0, 0, 0, 0);
            a1 = __builtin_amdgcn_mfma_f32_16x16x32_bf16(h1, wh[ks], a1, 0, 0, 0);
            a2 = __builtin_amdgcn_mfma_f32_16x16x32_bf16(h2, wh[ks], a2, 0, 0, 0);
            a3 = __builtin_amdgcn_mfma_f32_16x16x32_bf16(h3, wh[ks], a3, 0, 0, 0);
            a0 = __builtin_amdgcn_mfma_f32_16x16x32_bf16(h0, wl[ks], a0, 0, 0, 0);
            a1 = __builtin_amdgcn_mfma_f32_16x16x32_bf16(h1, wl[ks], a1, 0, 0, 0);
            a2 = __builtin_amdgcn_mfma_f32_16x16x32_bf16(h2, wl[ks], a2, 0, 0, 0);
            a3 = __builtin_amdgcn_mfma_f32_16x16x32_bf16(h3, wl[ks], a3, 0, 0, 0);
        }

        // wave partials -> LDS (buffer t&1)
        float* sr = sRed[t & 1];
#pragma unroll
        for (int r = 0; r < 4; ++r) {
            sr[(w * 64 +      q * 4 + r) * RSTR + nn] = a0[r];
            sr[(w * 64 + 16 + q * 4 + r) * RSTR + nn] = a1[r];
            sr[(w * 64 + 32 + q * 4 + r) * RSTR + nn] = a2[r];
            sr[(w * 64 + 48 + q * 4 + r) * RSTR + nn] = a3[r];
        }
        __syncthreads();   // sRed ready

        // reduce 4 waves, +bih, tanh, pack, 16-B sc1 write-through store
        if (tid < 128) {
            const int m  = tid >> 1;
            const int n0 = (tid & 1) * 8;
            floatx4 sA = *(const floatx4*)&sr[(0 * 64 + m) * RSTR + n0];
            floatx4 sB = *(const floatx4*)&sr[(0 * 64 + m) * RSTR + n0 + 4];
            sA += *(const floatx4*)&sr[(1 * 64 + m) * RSTR + n0];
            sB += *(const floatx4*)&sr[(1 * 64 + m) * RSTR + n0 + 4];
            sA += *(const floatx4*)&sr[(2 * 64 + m) * RSTR + n0];
            sB += *(const floatx4*)&sr[(2 * 64 + m) * RSTR + n0 + 4];
            sA += *(const floatx4*)&sr[(3 * 64 + m) * RSTR + n0];
            sB += *(const floatx4*)&sr[(3 * 64 + m) * RSTR + n0 + 4];
            unsigned short u0 = f2bf(fast_tanh(sA[0] + sBih[n0 + 0]));
            unsigned short u1 = f2bf(fast_tanh(sA[1] + sBih[n0 + 1]));
            unsigned short u2 = f2bf(fast_tanh(sA[2] + sBih[n0 + 2]));
            unsigned short u3 = f2bf(fast_tanh(sA[3] + sBih[n0 + 3]));
            unsigned short u4 = f2bf(fast_tanh(sB[0] + sBih[n0 + 4]));
            unsigned short u5 = f2bf(fast_tanh(sB[1] + sBih[n0 + 5]));
            unsigned short u6 = f2bf(fast_tanh(sB[2] + sBih[n0 + 6]));
            unsigned short u7 = f2bf(fast_tanh(sB[3] + sBih[n0 + 7]));
            uintx4 pk;
            pk.x = (unsigned)u0 | ((unsigned)u1 << 16);
            pk.y = (unsigned)u2 | ((unsigned)u3 << 16);
            pk.z = (unsigned)u4 | ((unsigned)u5 << 16);
            pk.w = (unsigned)u6 | ((unsigned)u7 << 16);
            unsigned short* dst =
                &hs[(size_t)(t + 1) * SLAB + (size_t)m * H_ + j0 + n0];
            asm volatile("global_store_dwordx4 %0, %1, off sc1"
                         :: "v"(dst), "v"(pk) : "memory");
        }

        // drain own stores, full-WG rendezvous, then MULTICAST the flag:
        // 8 lanes store (t+1) to the 8 replicated copies (4 KB apart).
        asm volatile("s_waitcnt vmcnt(0)" ::: "memory");
        __syncthreads();
        if (tid < 8)
            __hip_atomic_store(&flags[tid * FCPY + wg], (unsigned)(t + 1),
                               __ATOMIC_RELAXED, __HIP_MEMORY_SCOPE_AGENT);
    }
}

// ---- output projection: out[b,t,o] = hs[t+1][b,:] . Who[o,:] + bho ------
__global__ __launch_bounds__(NTHREADS) void k_out(
    const unsigned short* __restrict__ hflat, const unsigned short* __restrict__ who,
    const float* __restrict__ bho, float* __restrict__ out)
{
    const int tid = threadIdx.x;
    const int w = tid >> 6, lane = tid & 63, q = lane >> 4, nn = lane & 15;
    const size_t r0 = ((size_t)blockIdx.x * 4 + w) * 16;   // row = t*64+b
    floatx4 acc[8];
#pragma unroll
    for (int i = 0; i < 8; ++i) acc[i] = floatx4{0.f, 0.f, 0.f, 0.f};
    for (int ks = 0; ks < 64; ++ks) {
        const int kk = ks * 32 + q * 8;
        bf16x8 a = *(const bf16x8*)&hflat[(r0 + nn) * H_ + kk];
#pragma unroll
        for (int nt = 0; nt < 8; ++nt) {
            bf16x8 b = *(const bf16x8*)&who[(size_t)(nt * 16 + nn) * H_ + kk];
            acc[nt] = __builtin_amdgcn_mfma_f32_16x16x32_bf16(a, b, acc[nt], 0, 0, 0);
        }
    }
#pragma unroll
    for (int nt = 0; nt < 8; ++nt) {
#pragma unroll
        for (int r = 0; r < 4; ++r) {
            size_t rr = r0 + q * 4 + r;
            int t = (int)(rr >> 6), b = (int)(rr & 63);
            int o = nt * 16 + nn;
            out[(size_t)b * (S_ * O_) + (size_t)t * O_ + o] = acc[nt][r] + bho[o];
        }
    }
}

// ---- host ----------------------------------------------------------------
extern "C" void kernel_launch(void* const* d_in, const int* in_sizes, int n_in,
                              void* d_out, int out_size, void* d_ws, size_t ws_size,
                              hipStream_t stream) {
    const float* x    = (const float*)d_in[0];
    const float* Wih  = (const float*)d_in[1];
    const float* bih  = (const float*)d_in[2];
    const float* Whh  = (const float*)d_in[3];
    const float* Who  = (const float*)d_in[4];
    const float* bho  = (const float*)d_in[5];
    const float* mask = (const float*)d_in[6];
    float* out = (float*)d_out;

    char* ws = (char*)d_ws;
    constexpr size_t FLAGS_OFF   = 0;     // 8 copies x 4 KB = 32 KB
    constexpr size_t FLAGS_BYTES = 8 * FCPY * 4;
    constexpr size_t HS_OFF   = FLAGS_OFF + FLAGS_BYTES;
    constexpr size_t HS_BYTES = (size_t)(S_ + 1) * SLAB * 2;
    constexpr size_t WHI_OFF  = HS_OFF + HS_BYTES;
    constexpr size_t WLO_OFF  = WHI_OFF + (size_t)H_ * H_ * 2;
    constexpr size_t XBF_OFF  = WLO_OFF + (size_t)H_ * H_ * 2;
    constexpr size_t WIHH_OFF = XBF_OFF + (size_t)B_ * S_ * I_ * 2;
    constexpr size_t WIHL_OFF = WIHH_OFF + (size_t)H_ * I_ * 2;
    constexpr size_t WHO_OFF  = WIHL_OFF + (size_t)H_ * I_ * 2;
    constexpr size_t WS_NEED  = WHO_OFF + (size_t)O_ * H_ * 2;
    if (ws_size < WS_NEED) return;

    unsigned int*   flags = (unsigned int*)(ws + FLAGS_OFF);
    unsigned short* hs    = (unsigned short*)(ws + HS_OFF);
    unsigned short* whi   = (unsigned short*)(ws + WHI_OFF);
    unsigned short* wlo   = (unsigned short*)(ws + WLO_OFF);
    unsigned short* xbf   = (unsigned short*)(ws + XBF_OFF);
    unsigned short* wihh  = (unsigned short*)(ws + WIHH_OFF);
    unsigned short* wihl  = (unsigned short*)(ws + WIHL_OFF);
    unsigned short* whobf = (unsigned short*)(ws + WHO_OFF);

    hipMemsetAsync(flags, 0, FLAGS_BYTES, stream);        // flag copies = 0
    hipMemsetAsync(hs, 0, (size_t)SLAB * 2, stream);      // h(0) = 0

    k_wsplit<<<1024, 256, 0, stream>>>(Whh, mask, whi, wlo, H_ * H_);
    k_split <<<256, 256, 0, stream>>>(Wih, wihh, wihl, H_ * I_);
    k_cast  <<<256, 256, 0, stream>>>(Who, whobf, O_ * H_);
    k_cast  <<<1024, 256, 0, stream>>>(x, xbf, B_ * S_ * I_);

    k_rnn<<<NWG, NTHREADS, 0, stream>>>(whi, wlo, wihh, wihl, xbf, bih, hs, flags);
    k_out<<<512, NTHREADS, 0, stream>>>(hs + SLAB, whobf, bho, out);
}